// Round 4
// baseline (722.750 us; speedup 1.0000x reference)
//
#include <hip/hip_runtime.h>
#include <hip/hip_fp16.h>

#define NCH 128
#define BCAP 1280   // bucket capacity: mean 1024, std 32 -> +8 sigma

typedef __attribute__((ext_vector_type(8))) short short8;
typedef __attribute__((ext_vector_type(4))) float floatx4;

static inline size_t align256(size_t x){ return (x + 255) & ~(size_t)255; }

// ---------------- bucketed CSR build ----------------
// Pass A: bin edges by col>>6. Packed 4B record: (col&63)<<17 | row  (row < 2^17).
// Appends into bucket-local regions -> ~1563 hot lines, L2-resident, ~8MB HBM write
// (vs 102MB for the old full-random 4B scatter).
__global__ void bucketA_kernel(const int* __restrict__ row, const int* __restrict__ col,
                               int* __restrict__ bcur, unsigned* __restrict__ bucketed, int E){
  int e = blockIdx.x * blockDim.x + threadIdx.x;
  if (e < E){
    int r = row[e], c = col[e];
    int b = c >> 6;
    int pos = atomicAdd(&bcur[b], 1);
    if (pos < BCAP) bucketed[(size_t)b * BCAP + pos] = (unsigned)r | ((unsigned)(c & 63) << 17);
  }
}

// exclusive scan of clamped bucket sizes -> slab base in rows_sorted. One block.
__global__ void bscan_kernel(const int* __restrict__ bcur, int* __restrict__ bbase, int nbuckets){
  __shared__ int sh[256];
  __shared__ int carry;
  int t = threadIdx.x;
  if (t == 0) carry = 0;
  __syncthreads();
  for (int start = 0; start < nbuckets; start += 256){
    int i = start + t;
    int v = (i < nbuckets) ? min(bcur[i], BCAP) : 0;
    int orig = v;
    sh[t] = v; __syncthreads();
    for (int off = 1; off < 256; off <<= 1){
      int val = (t >= off) ? sh[t - off] : 0;
      __syncthreads();
      sh[t] += val;
      __syncthreads();
    }
    int ex = sh[t] - orig + carry;
    if (i < nbuckets) bbase[i] = ex;
    __syncthreads();
    if (t == 255) carry += sh[255];
    __syncthreads();
  }
}

// Pass B: one block per bucket. LDS counting-sort by col; emit counts/offs/dinv
// (coalesced, bucket owns cols b*64..b*64+63) and the sorted rows_sorted slab.
__global__ __launch_bounds__(256) void bucketB_kernel(
    const unsigned* __restrict__ bucketed, const int* __restrict__ bcur,
    const int* __restrict__ bbase, int* __restrict__ rows_sorted,
    int* __restrict__ offs, int* __restrict__ counts, float* __restrict__ dinv, int N){
  __shared__ int lrow[BCAP];
  __shared__ int lcol[BCAP];
  __shared__ int lsort[BCAP];
  __shared__ int cnt[64];
  __shared__ int cnt2[64];
  __shared__ int lex[64];
  int b = blockIdx.x;
  int t = threadIdx.x;
  int size = min(bcur[b], BCAP);
  int base = bbase[b];
  int n0 = b << 6;
  if (t < 64){ cnt[t] = 0; cnt2[t] = 0; }
  __syncthreads();
  for (int i = t; i < size; i += 256){
    unsigned v = bucketed[(size_t)b * BCAP + i];
    int r  = (int)(v & 0x1FFFFu);
    int cl = (int)(v >> 17);
    lrow[i] = r;
    lcol[i] = cl;
    atomicAdd(&cnt[cl], 1);
  }
  __syncthreads();
  if (t < 64){                       // wave 0: exclusive scan of 64 counters
    int v = cnt[t];
    int inc = v;
    #pragma unroll
    for (int off = 1; off < 64; off <<= 1){
      int o = __shfl_up(inc, off, 64);
      if (t >= off) inc += o;
    }
    lex[t] = inc - v;
    if (n0 + t < N){
      counts[n0 + t] = v;
      offs[n0 + t]   = base + (inc - v);
      dinv[n0 + t]   = rsqrtf((float)v + 1.0f);
    }
  }
  __syncthreads();
  for (int i = t; i < size; i += 256){
    int cl = lcol[i];
    int pos = lex[cl] + atomicAdd(&cnt2[cl], 1);
    lsort[pos] = lrow[i];
  }
  __syncthreads();
  for (int i = t; i < size; i += 256) rows_sorted[base + i] = lsort[i];
}

// ---------------- W split-transpose prep ----------------
// src: fp32 [128k][128n] row-major. dst: bf16 hi/lo planes [n][k] (k-contiguous).
__global__ void wsplit_kernel(const float* __restrict__ src,
                              short* __restrict__ dsthi, short* __restrict__ dstlo){
  int idx = blockIdx.x * blockDim.x + threadIdx.x;   // 0..16383
  int k = idx >> 7, n = idx & 127;
  float x = src[idx];
  unsigned u = __float_as_uint(x);
  short hs = (short)(u >> 16);                       // truncated bf16 hi
  float hf = __uint_as_float(u & 0xFFFF0000u);
  float lf = x - hf;                                 // exact residual
  short ls = (short)(__float_as_uint(lf) >> 16);     // bf16 lo
  dsthi[n * 128 + k] = hs;
  dstlo[n * 128 + k] = ls;
}

// ---------------- GEMM: [nrows,128] @ [128,128], split-bf16 MFMA ----------------
#define KST 40
__global__ __launch_bounds__(256, 2) void gemm_mfma(
    const float* __restrict__ X, const short* __restrict__ Wthi,
    const short* __restrict__ Wtlo, const float* __restrict__ scale,
    __half* __restrict__ O, int nrows, int do_scale){
  __shared__ short Xhi[128 * KST];
  __shared__ short Xlo[128 * KST];
  __shared__ short Whi[128 * KST];
  __shared__ short Wlo[128 * KST];
  int t = threadIdx.x;
  int w = t >> 6;            // wave 0..3 -> rows w*32..w*32+31
  int lane = t & 63;
  int m = lane & 15;
  int q = lane >> 4;
  int row0 = blockIdx.x * 128;

  floatx4 acc[2][8];
  #pragma unroll
  for (int rt = 0; rt < 2; rt++)
    #pragma unroll
    for (int ct = 0; ct < 8; ct++) acc[rt][ct] = (floatx4)0.f;

  for (int kc = 0; kc < 4; kc++){
    int k0 = kc * 32;
    __syncthreads();
    #pragma unroll
    for (int qq = 0; qq < 4; qq++){
      int f = t + 256 * qq;
      int r = f >> 3;
      int kq = f & 7;
      int gr = row0 + r;
      int grc = (gr < nrows) ? gr : 0;
      float4 v = *(const float4*)(X + (size_t)grc * NCH + k0 + kq * 4);
      short h[4], l[4];
      float vv[4] = {v.x, v.y, v.z, v.w};
      #pragma unroll
      for (int j = 0; j < 4; j++){
        unsigned u = __float_as_uint(vv[j]);
        h[j] = (short)(u >> 16);
        float hf = __uint_as_float(u & 0xFFFF0000u);
        l[j] = (short)(__float_as_uint(vv[j] - hf) >> 16);
      }
      *(uint2*)(Xhi + r * KST + kq * 4) = *(uint2*)h;
      *(uint2*)(Xlo + r * KST + kq * 4) = *(uint2*)l;
    }
    #pragma unroll
    for (int qq = 0; qq < 4; qq++){
      int u = t + 256 * qq;
      int n = u >> 3, kq = u & 7;
      *(uint2*)(Whi + n * KST + kq * 4) = *(const uint2*)(Wthi + n * 128 + k0 + kq * 4);
      *(uint2*)(Wlo + n * KST + kq * 4) = *(const uint2*)(Wtlo + n * 128 + k0 + kq * 4);
    }
    __syncthreads();

    short8 a_hi0 = *(const short8*)(Xhi + (w * 32 + m) * KST + q * 8);
    short8 a_hi1 = *(const short8*)(Xhi + (w * 32 + 16 + m) * KST + q * 8);
    short8 a_lo0 = *(const short8*)(Xlo + (w * 32 + m) * KST + q * 8);
    short8 a_lo1 = *(const short8*)(Xlo + (w * 32 + 16 + m) * KST + q * 8);
    #pragma unroll
    for (int ct = 0; ct < 8; ct++){
      short8 b_hi = *(const short8*)(Whi + (ct * 16 + m) * KST + q * 8);
      short8 b_lo = *(const short8*)(Wlo + (ct * 16 + m) * KST + q * 8);
      acc[0][ct] = __builtin_amdgcn_mfma_f32_16x16x32_bf16(a_hi0, b_hi, acc[0][ct], 0, 0, 0);
      acc[0][ct] = __builtin_amdgcn_mfma_f32_16x16x32_bf16(a_lo0, b_hi, acc[0][ct], 0, 0, 0);
      acc[0][ct] = __builtin_amdgcn_mfma_f32_16x16x32_bf16(a_hi0, b_lo, acc[0][ct], 0, 0, 0);
      acc[1][ct] = __builtin_amdgcn_mfma_f32_16x16x32_bf16(a_hi1, b_hi, acc[1][ct], 0, 0, 0);
      acc[1][ct] = __builtin_amdgcn_mfma_f32_16x16x32_bf16(a_lo1, b_hi, acc[1][ct], 0, 0, 0);
      acc[1][ct] = __builtin_amdgcn_mfma_f32_16x16x32_bf16(a_hi1, b_lo, acc[1][ct], 0, 0, 0);
    }
  }
  #pragma unroll
  for (int rt = 0; rt < 2; rt++){
    #pragma unroll
    for (int r = 0; r < 4; r++){
      int grow = row0 + w * 32 + rt * 16 + q * 4 + r;
      if (grow < nrows){
        float sc = do_scale ? scale[grow] : 1.0f;
        #pragma unroll
        for (int ct = 0; ct < 8; ct++){
          int gcol = ct * 16 + m;
          O[(size_t)grow * NCH + gcol] = __float2half(acc[rt][ct][r] * sc);
        }
      }
    }
  }
}

// ---------------- GCN aggregation: one wave per node, fp16 gathers ----------------
__global__ __launch_bounds__(256) void agg_kernel(
    const __half2* __restrict__ s2, const float* __restrict__ dinv,
    const int* __restrict__ offs, const int* __restrict__ counts,
    const int* __restrict__ rows_sorted, const float* __restrict__ bias,
    float* __restrict__ outp, int N, int do_relu){
  int wave = (int)((blockIdx.x * blockDim.x + threadIdx.x) >> 6);
  int lane = threadIdx.x & 63;
  if (wave >= N) return;
  int c = wave;
  float2 self = __half22float2(s2[(size_t)c * 64 + lane]);
  float ax = self.x, ay = self.y;
  int off = offs[c], cnt = counts[c];
  for (int chunk = 0; chunk < cnt; chunk += 64){
    int nn = min(64, cnt - chunk);
    int myidx = (lane < nn) ? rows_sorted[off + chunk + lane] : 0;
    int e = 0;
    for (; e + 8 <= nn; e += 8){
      int r0 = __shfl(myidx, e + 0, 64);
      int r1 = __shfl(myidx, e + 1, 64);
      int r2 = __shfl(myidx, e + 2, 64);
      int r3 = __shfl(myidx, e + 3, 64);
      int r4 = __shfl(myidx, e + 4, 64);
      int r5 = __shfl(myidx, e + 5, 64);
      int r6 = __shfl(myidx, e + 6, 64);
      int r7 = __shfl(myidx, e + 7, 64);
      __half2 v0 = s2[(size_t)r0 * 64 + lane];
      __half2 v1 = s2[(size_t)r1 * 64 + lane];
      __half2 v2 = s2[(size_t)r2 * 64 + lane];
      __half2 v3 = s2[(size_t)r3 * 64 + lane];
      __half2 v4 = s2[(size_t)r4 * 64 + lane];
      __half2 v5 = s2[(size_t)r5 * 64 + lane];
      __half2 v6 = s2[(size_t)r6 * 64 + lane];
      __half2 v7 = s2[(size_t)r7 * 64 + lane];
      float2 f0 = __half22float2(v0), f1 = __half22float2(v1);
      float2 f2 = __half22float2(v2), f3 = __half22float2(v3);
      float2 f4 = __half22float2(v4), f5 = __half22float2(v5);
      float2 f6 = __half22float2(v6), f7 = __half22float2(v7);
      ax += f0.x + f1.x + f2.x + f3.x + f4.x + f5.x + f6.x + f7.x;
      ay += f0.y + f1.y + f2.y + f3.y + f4.y + f5.y + f6.y + f7.y;
    }
    for (; e < nn; e++){
      int r = __shfl(myidx, e, 64);
      float2 f = __half22float2(s2[(size_t)r * 64 + lane]);
      ax += f.x; ay += f.y;
    }
  }
  float di = dinv[c];
  float2 bv = ((const float2*)bias)[lane];
  float ox = di * ax + bv.x;
  float oy = di * ay + bv.y;
  if (do_relu){ ox = fmaxf(ox, 0.f); oy = fmaxf(oy, 0.f); }
  ((float2*)outp)[(size_t)c * 64 + lane] = make_float2(ox, oy);
}

// ---------------- Pair head: wave per 2 pairs, fp16 gathers ----------------
__global__ __launch_bounds__(256) void pair_kernel(
    const __half2* __restrict__ A2, const __half2* __restrict__ B2,
    const int* __restrict__ src, const int* __restrict__ dst,
    const float* __restrict__ bm1, const float* __restrict__ Wm2,
    const float* __restrict__ bm2, float* __restrict__ outp, int P){
  int gwave = (int)((blockIdx.x * blockDim.x + threadIdx.x) >> 6);
  int lane  = threadIdx.x & 63;
  int nw    = (int)((gridDim.x * blockDim.x) >> 6);
  float2 bb = ((const float2*)bm1)[lane];
  float2 ww = ((const float2*)Wm2)[lane];
  float bsc = bm2[0];
  for (int p = gwave * 2; p < P; p += nw * 2){
    int p1ok = (p + 1 < P);
    int s0 = src[p], d0 = dst[p];
    int s1 = p1ok ? src[p + 1] : s0;
    int d1 = p1ok ? dst[p + 1] : d0;
    float2 a0 = __half22float2(A2[(size_t)s0 * 64 + lane]);
    float2 b0 = __half22float2(B2[(size_t)d0 * 64 + lane]);
    float2 a1 = __half22float2(A2[(size_t)s1 * 64 + lane]);
    float2 b1 = __half22float2(B2[(size_t)d1 * 64 + lane]);
    float zx0 = fmaxf(a0.x + b0.x + bb.x, 0.f);
    float zy0 = fmaxf(a0.y + b0.y + bb.y, 0.f);
    float zx1 = fmaxf(a1.x + b1.x + bb.x, 0.f);
    float zy1 = fmaxf(a1.y + b1.y + bb.y, 0.f);
    float v0 = zx0 * ww.x + zy0 * ww.y;
    float v1 = zx1 * ww.x + zy1 * ww.y;
    #pragma unroll
    for (int off = 32; off > 0; off >>= 1){
      v0 += __shfl_down(v0, off, 64);
      v1 += __shfl_down(v1, off, 64);
    }
    if (lane == 0){
      outp[p] = v0 + bsc;
      if (p1ok) outp[p + 1] = v1 + bsc;
    }
  }
}

// ---------------- launch ----------------

extern "C" void kernel_launch(void* const* d_in, const int* in_sizes, int n_in,
                              void* d_out, int out_size, void* d_ws, size_t ws_size,
                              hipStream_t stream){
  const float* x   = (const float*)d_in[0];
  const int*   ei  = (const int*)  d_in[1];
  const int*   ep  = (const int*)  d_in[2];
  const float* W1  = (const float*)d_in[3];
  const float* b1  = (const float*)d_in[4];
  const float* W2  = (const float*)d_in[5];
  const float* b2  = (const float*)d_in[6];
  const float* Wm1 = (const float*)d_in[7];
  const float* bm1 = (const float*)d_in[8];
  const float* Wm2 = (const float*)d_in[9];
  const float* bm2 = (const float*)d_in[10];
  float* outp = (float*)d_out;

  const int N = in_sizes[0] / NCH;
  const int E = in_sizes[1] / 2;
  const int P = in_sizes[2] / 2;
  const int nbuckets = (N + 63) / 64;

  // workspace layout
  char* base = (char*)d_ws;
  size_t off = 0;
  int*      counts      = (int*)     (base + off); off = align256(off + (size_t)N * 4);
  int*      offs        = (int*)     (base + off); off = align256(off + (size_t)N * 4);
  float*    dinv        = (float*)   (base + off); off = align256(off + (size_t)N * 4);
  int*      bcur        = (int*)     (base + off); off = align256(off + (size_t)nbuckets * 4);
  int*      bbase       = (int*)     (base + off); off = align256(off + (size_t)nbuckets * 4);
  unsigned* bucketed    = (unsigned*)(base + off); off = align256(off + (size_t)nbuckets * BCAP * 4);
  int*      rows_sorted = (int*)     (base + off); off = align256(off + (size_t)E * 4);
  short*    wt_planes   = (short*)   (base + off); off = align256(off + (size_t)8 * 128 * 128 * 2);
  float*    hbuf        = (float*)   (base + off); off = align256(off + (size_t)N * NCH * 4);
  __half*   sA          = (__half*)  (base + off); off = align256(off + (size_t)N * NCH * 2);
  __half*   sB          = (__half*)  (base + off); off = align256(off + (size_t)N * NCH * 2);
  (void)ws_size; (void)n_in; (void)out_size;

  short* W1hi  = wt_planes + 0 * 16384;
  short* W1lo  = wt_planes + 1 * 16384;
  short* W2hi  = wt_planes + 2 * 16384;
  short* W2lo  = wt_planes + 3 * 16384;
  short* Wm1ahi= wt_planes + 4 * 16384;
  short* Wm1alo= wt_planes + 5 * 16384;
  short* Wm1bhi= wt_planes + 6 * 16384;
  short* Wm1blo= wt_planes + 7 * 16384;

  const int* row = ei;         // edge_index[0] = source
  const int* col = ei + E;     // edge_index[1] = target
  const int* psrc = ep;
  const int* pdst = ep + P;

  hipMemsetAsync(bcur, 0, (size_t)nbuckets * 4, stream);

  bucketA_kernel<<<(E + 255) / 256, 256, 0, stream>>>(row, col, bcur, bucketed, E);
  bscan_kernel  <<<1, 256, 0, stream>>>(bcur, bbase, nbuckets);
  bucketB_kernel<<<nbuckets, 256, 0, stream>>>(bucketed, bcur, bbase, rows_sorted,
                                               offs, counts, dinv, N);

  wsplit_kernel<<<64, 256, 0, stream>>>(W1,              W1hi,   W1lo);
  wsplit_kernel<<<64, 256, 0, stream>>>(W2,              W2hi,   W2lo);
  wsplit_kernel<<<64, 256, 0, stream>>>(Wm1,             Wm1ahi, Wm1alo);
  wsplit_kernel<<<64, 256, 0, stream>>>(Wm1 + 128 * 128, Wm1bhi, Wm1blo);

  int gemm_grid = (N + 127) / 128;
  int agg_grid  = (N + 3) / 4;

  // conv1: s1 = fp16(dinv * (x@W1));  h1 = relu(dinv*(s1[c] + sum s1[r]) + b1)
  gemm_mfma<<<gemm_grid, 256, 0, stream>>>(x, W1hi, W1lo, dinv, sA, N, 1);
  agg_kernel<<<agg_grid, 256, 0, stream>>>((const __half2*)sA, dinv, offs, counts, rows_sorted, b1, hbuf, N, 1);
  // conv2: s2 = fp16(dinv * (h1@W2)); h2 = dinv*(s2[c] + sum s2[r]) + b2
  gemm_mfma<<<gemm_grid, 256, 0, stream>>>(hbuf, W2hi, W2lo, dinv, sB, N, 1);
  agg_kernel<<<agg_grid, 256, 0, stream>>>((const __half2*)sB, dinv, offs, counts, rows_sorted, b2, hbuf, N, 0);
  // pair head precompute: A = h2 @ Wm1[:128], B = h2 @ Wm1[128:]  (fp16)
  gemm_mfma<<<gemm_grid, 256, 0, stream>>>(hbuf, Wm1ahi, Wm1alo, dinv, sA, N, 0);
  gemm_mfma<<<gemm_grid, 256, 0, stream>>>(hbuf, Wm1bhi, Wm1blo, dinv, sB, N, 0);
  // out[p] = relu(A[src]+B[dst]+bm1) @ Wm2 + bm2
  pair_kernel<<<8192, 256, 0, stream>>>((const __half2*)sA, (const __half2*)sB, psrc, pdst, bm1, Wm2, bm2, outp, P);
}

// Round 5
// 501.933 us; speedup vs baseline: 1.4399x; 1.4399x over previous
//
#include <hip/hip_runtime.h>
#include <hip/hip_fp16.h>

#define NCH 128
#define G_NODES 256      // nodes per bucket
#define EPB 4096         // edges per block, pass A
#define RCAP 4864        // per-bucket edge capacity (mean 4096, sigma 64 -> +12 sigma)
#define MAXNB 512        // max buckets supported by LDS arrays (N <= 128k)

typedef __attribute__((ext_vector_type(8))) short short8;
typedef __attribute__((ext_vector_type(4))) float floatx4;

static inline size_t align256(size_t x){ return (x + 255) & ~(size_t)255; }

// ---------------- Pass A: LDS-binned edge bucketing ----------------
// Per block: 4096 edges -> 391 bins (col>>8) fully in LDS, one global atomic
// per (block,bin) to reserve a contiguous run, then coalesced run writes.
// Record: row (17b) | (col&255)<<17.
__global__ __launch_bounds__(256) void binA_kernel(
    const int* __restrict__ row, const int* __restrict__ col,
    int* __restrict__ gcur, unsigned* __restrict__ bucketed, int E, int NB){
  __shared__ int cnt[MAXNB];
  __shared__ int lbase[MAXNB];
  __shared__ int gbase[MAXNB];
  __shared__ unsigned sorted[EPB];
  __shared__ unsigned short binOf[EPB];
  __shared__ int sh[256];
  __shared__ int carry;
  int t = threadIdx.x;
  int e0 = blockIdx.x * EPB;
  int ecnt = min(EPB, E - e0);
  for (int i = t; i < NB; i += 256) cnt[i] = 0;
  if (t == 0) carry = 0;
  __syncthreads();
  unsigned rec[16]; int bn[16]; int rk[16];
  #pragma unroll
  for (int i = 0; i < 16; i++){
    int e = e0 + i * 256 + t;
    if (e < E){
      int r = row[e], c = col[e];
      bn[i]  = c >> 8;
      rec[i] = (unsigned)r | ((unsigned)(c & 255) << 17);
      rk[i]  = atomicAdd(&cnt[bn[i]], 1);
    } else bn[i] = -1;
  }
  __syncthreads();
  // exclusive scan cnt -> lbase (chunks of 256 with carry)
  for (int start = 0; start < NB; start += 256){
    int i = start + t;
    int v = (i < NB) ? cnt[i] : 0;
    sh[t] = v; __syncthreads();
    for (int off = 1; off < 256; off <<= 1){
      int val = (t >= off) ? sh[t - off] : 0;
      __syncthreads(); sh[t] += val; __syncthreads();
    }
    if (i < NB) lbase[i] = sh[t] - v + carry;
    __syncthreads();
    if (t == 255) carry += sh[255];
    __syncthreads();
  }
  // reserve global runs: one atomic per non-empty bin
  for (int i = t; i < NB; i += 256){
    int c = cnt[i];
    gbase[i] = (c > 0) ? atomicAdd(&gcur[i], c) : 0;
  }
  __syncthreads();
  // scatter into LDS bin-sorted order
  #pragma unroll
  for (int i = 0; i < 16; i++){
    if (bn[i] >= 0){
      int pos = lbase[bn[i]] + rk[i];
      sorted[pos] = rec[i];
      binOf[pos]  = (unsigned short)bn[i];
    }
  }
  __syncthreads();
  // coalesced run writes
  for (int idx = t; idx < ecnt; idx += 256){
    int b = binOf[idx];
    int gpos = gbase[b] + (idx - lbase[b]);
    if (gpos < RCAP) bucketed[(size_t)b * RCAP + gpos] = sorted[idx];
  }
}

// exclusive scan of clamped bucket sizes -> slab base. One block.
__global__ void bscan_kernel(const int* __restrict__ gcur, int* __restrict__ bbase, int nb){
  __shared__ int sh[256];
  __shared__ int carry;
  int t = threadIdx.x;
  if (t == 0) carry = 0;
  __syncthreads();
  for (int start = 0; start < nb; start += 256){
    int i = start + t;
    int v = (i < nb) ? min(gcur[i], RCAP) : 0;
    int orig = v;
    sh[t] = v; __syncthreads();
    for (int off = 1; off < 256; off <<= 1){
      int val = (t >= off) ? sh[t - off] : 0;
      __syncthreads(); sh[t] += val; __syncthreads();
    }
    if (i < nb) bbase[i] = sh[t] - orig + carry;
    __syncthreads();
    if (t == 255) carry += sh[255];
    __syncthreads();
  }
}

// ---------------- Pass B: per-bucket LDS counting sort -> final CSR ----------------
__global__ __launch_bounds__(256) void binB_kernel(
    const unsigned* __restrict__ bucketed, const int* __restrict__ gcur,
    const int* __restrict__ bbase, int* __restrict__ rows_sorted,
    int* __restrict__ offs, int* __restrict__ counts, float* __restrict__ dinv, int N){
  __shared__ unsigned ledge[RCAP];
  __shared__ int cnt[G_NODES];
  __shared__ int cnt2[G_NODES];
  __shared__ int lex[G_NODES];
  __shared__ int sh[256];
  int b = blockIdx.x, t = threadIdx.x;
  int size = min(gcur[b], RCAP);
  int base = bbase[b];
  int n0 = b * G_NODES;
  cnt[t] = 0; cnt2[t] = 0;
  __syncthreads();
  for (int i = t; i < size; i += 256){
    unsigned v = bucketed[(size_t)b * RCAP + i];
    ledge[i] = v;
    atomicAdd(&cnt[v >> 17], 1);
  }
  __syncthreads();
  {
    int v = cnt[t];
    sh[t] = v; __syncthreads();
    for (int off = 1; off < 256; off <<= 1){
      int val = (t >= off) ? sh[t - off] : 0;
      __syncthreads(); sh[t] += val; __syncthreads();
    }
    lex[t] = sh[t] - v;
    int n = n0 + t;
    if (n < N){
      counts[n] = v;
      offs[n]   = base + sh[t] - v;
      dinv[n]   = rsqrtf((float)v + 1.0f);
    }
  }
  __syncthreads();
  for (int i = t; i < size; i += 256){
    unsigned v = ledge[i];
    int node = v >> 17;
    int pos = lex[node] + atomicAdd(&cnt2[node], 1);
    rows_sorted[base + pos] = (int)(v & 0x1FFFFu);   // writes confined to this block's slab
  }
}

// ---------------- W split-transpose prep ----------------
__global__ void wsplit_kernel(const float* __restrict__ src,
                              short* __restrict__ dsthi, short* __restrict__ dstlo){
  int idx = blockIdx.x * blockDim.x + threadIdx.x;   // 0..16383
  int k = idx >> 7, n = idx & 127;
  float x = src[idx];
  unsigned u = __float_as_uint(x);
  short hs = (short)(u >> 16);
  float hf = __uint_as_float(u & 0xFFFF0000u);
  float lf = x - hf;
  short ls = (short)(__float_as_uint(lf) >> 16);
  dsthi[n * 128 + k] = hs;
  dstlo[n * 128 + k] = ls;
}

// ---------------- GEMM: [nrows,128] @ [128,128], split-bf16 MFMA ----------------
#define KST 40
__global__ __launch_bounds__(256, 2) void gemm_mfma(
    const float* __restrict__ X, const short* __restrict__ Wthi,
    const short* __restrict__ Wtlo, const float* __restrict__ scale,
    __half* __restrict__ O, int nrows, int do_scale){
  __shared__ short Xhi[128 * KST];
  __shared__ short Xlo[128 * KST];
  __shared__ short Whi[128 * KST];
  __shared__ short Wlo[128 * KST];
  int t = threadIdx.x;
  int w = t >> 6;
  int lane = t & 63;
  int m = lane & 15;
  int q = lane >> 4;
  int row0 = blockIdx.x * 128;

  floatx4 acc[2][8];
  #pragma unroll
  for (int rt = 0; rt < 2; rt++)
    #pragma unroll
    for (int ct = 0; ct < 8; ct++) acc[rt][ct] = (floatx4)0.f;

  for (int kc = 0; kc < 4; kc++){
    int k0 = kc * 32;
    __syncthreads();
    #pragma unroll
    for (int qq = 0; qq < 4; qq++){
      int f = t + 256 * qq;
      int r = f >> 3;
      int kq = f & 7;
      int gr = row0 + r;
      int grc = (gr < nrows) ? gr : 0;
      float4 v = *(const float4*)(X + (size_t)grc * NCH + k0 + kq * 4);
      short h[4], l[4];
      float vv[4] = {v.x, v.y, v.z, v.w};
      #pragma unroll
      for (int j = 0; j < 4; j++){
        unsigned u = __float_as_uint(vv[j]);
        h[j] = (short)(u >> 16);
        float hf = __uint_as_float(u & 0xFFFF0000u);
        l[j] = (short)(__float_as_uint(vv[j] - hf) >> 16);
      }
      *(uint2*)(Xhi + r * KST + kq * 4) = *(uint2*)h;
      *(uint2*)(Xlo + r * KST + kq * 4) = *(uint2*)l;
    }
    #pragma unroll
    for (int qq = 0; qq < 4; qq++){
      int u = t + 256 * qq;
      int n = u >> 3, kq = u & 7;
      *(uint2*)(Whi + n * KST + kq * 4) = *(const uint2*)(Wthi + n * 128 + k0 + kq * 4);
      *(uint2*)(Wlo + n * KST + kq * 4) = *(const uint2*)(Wtlo + n * 128 + k0 + kq * 4);
    }
    __syncthreads();

    short8 a_hi0 = *(const short8*)(Xhi + (w * 32 + m) * KST + q * 8);
    short8 a_hi1 = *(const short8*)(Xhi + (w * 32 + 16 + m) * KST + q * 8);
    short8 a_lo0 = *(const short8*)(Xlo + (w * 32 + m) * KST + q * 8);
    short8 a_lo1 = *(const short8*)(Xlo + (w * 32 + 16 + m) * KST + q * 8);
    #pragma unroll
    for (int ct = 0; ct < 8; ct++){
      short8 b_hi = *(const short8*)(Whi + (ct * 16 + m) * KST + q * 8);
      short8 b_lo = *(const short8*)(Wlo + (ct * 16 + m) * KST + q * 8);
      acc[0][ct] = __builtin_amdgcn_mfma_f32_16x16x32_bf16(a_hi0, b_hi, acc[0][ct], 0, 0, 0);
      acc[0][ct] = __builtin_amdgcn_mfma_f32_16x16x32_bf16(a_lo0, b_hi, acc[0][ct], 0, 0, 0);
      acc[0][ct] = __builtin_amdgcn_mfma_f32_16x16x32_bf16(a_hi0, b_lo, acc[0][ct], 0, 0, 0);
      acc[1][ct] = __builtin_amdgcn_mfma_f32_16x16x32_bf16(a_hi1, b_hi, acc[1][ct], 0, 0, 0);
      acc[1][ct] = __builtin_amdgcn_mfma_f32_16x16x32_bf16(a_lo1, b_hi, acc[1][ct], 0, 0, 0);
      acc[1][ct] = __builtin_amdgcn_mfma_f32_16x16x32_bf16(a_hi1, b_lo, acc[1][ct], 0, 0, 0);
    }
  }
  #pragma unroll
  for (int rt = 0; rt < 2; rt++){
    #pragma unroll
    for (int r = 0; r < 4; r++){
      int grow = row0 + w * 32 + rt * 16 + q * 4 + r;
      if (grow < nrows){
        float sc = do_scale ? scale[grow] : 1.0f;
        #pragma unroll
        for (int ct = 0; ct < 8; ct++){
          int gcol = ct * 16 + m;
          O[(size_t)grow * NCH + gcol] = __float2half(acc[rt][ct][r] * sc);
        }
      }
    }
  }
}

// ---------------- GCN aggregation: one wave per node, fp16 gathers ----------------
__global__ __launch_bounds__(256) void agg_kernel(
    const __half2* __restrict__ s2, const float* __restrict__ dinv,
    const int* __restrict__ offs, const int* __restrict__ counts,
    const int* __restrict__ rows_sorted, const float* __restrict__ bias,
    float* __restrict__ outp, int N, int do_relu){
  int wave = (int)((blockIdx.x * blockDim.x + threadIdx.x) >> 6);
  int lane = threadIdx.x & 63;
  if (wave >= N) return;
  int c = wave;
  float2 self = __half22float2(s2[(size_t)c * 64 + lane]);
  float ax = self.x, ay = self.y;
  int off = offs[c], cnt = counts[c];
  for (int chunk = 0; chunk < cnt; chunk += 64){
    int nn = min(64, cnt - chunk);
    int myidx = (lane < nn) ? rows_sorted[off + chunk + lane] : 0;
    int e = 0;
    for (; e + 8 <= nn; e += 8){
      int r0 = __shfl(myidx, e + 0, 64);
      int r1 = __shfl(myidx, e + 1, 64);
      int r2 = __shfl(myidx, e + 2, 64);
      int r3 = __shfl(myidx, e + 3, 64);
      int r4 = __shfl(myidx, e + 4, 64);
      int r5 = __shfl(myidx, e + 5, 64);
      int r6 = __shfl(myidx, e + 6, 64);
      int r7 = __shfl(myidx, e + 7, 64);
      __half2 v0 = s2[(size_t)r0 * 64 + lane];
      __half2 v1 = s2[(size_t)r1 * 64 + lane];
      __half2 v2 = s2[(size_t)r2 * 64 + lane];
      __half2 v3 = s2[(size_t)r3 * 64 + lane];
      __half2 v4 = s2[(size_t)r4 * 64 + lane];
      __half2 v5 = s2[(size_t)r5 * 64 + lane];
      __half2 v6 = s2[(size_t)r6 * 64 + lane];
      __half2 v7 = s2[(size_t)r7 * 64 + lane];
      float2 f0 = __half22float2(v0), f1 = __half22float2(v1);
      float2 f2 = __half22float2(v2), f3 = __half22float2(v3);
      float2 f4 = __half22float2(v4), f5 = __half22float2(v5);
      float2 f6 = __half22float2(v6), f7 = __half22float2(v7);
      ax += f0.x + f1.x + f2.x + f3.x + f4.x + f5.x + f6.x + f7.x;
      ay += f0.y + f1.y + f2.y + f3.y + f4.y + f5.y + f6.y + f7.y;
    }
    for (; e < nn; e++){
      int r = __shfl(myidx, e, 64);
      float2 f = __half22float2(s2[(size_t)r * 64 + lane]);
      ax += f.x; ay += f.y;
    }
  }
  float di = dinv[c];
  float2 bv = ((const float2*)bias)[lane];
  float ox = di * ax + bv.x;
  float oy = di * ay + bv.y;
  if (do_relu){ ox = fmaxf(ox, 0.f); oy = fmaxf(oy, 0.f); }
  ((float2*)outp)[(size_t)c * 64 + lane] = make_float2(ox, oy);
}

// ---------------- Pair head: wave per 2 pairs, fp16 gathers ----------------
__global__ __launch_bounds__(256) void pair_kernel(
    const __half2* __restrict__ A2, const __half2* __restrict__ B2,
    const int* __restrict__ src, const int* __restrict__ dst,
    const float* __restrict__ bm1, const float* __restrict__ Wm2,
    const float* __restrict__ bm2, float* __restrict__ outp, int P){
  int gwave = (int)((blockIdx.x * blockDim.x + threadIdx.x) >> 6);
  int lane  = threadIdx.x & 63;
  int nw    = (int)((gridDim.x * blockDim.x) >> 6);
  float2 bb = ((const float2*)bm1)[lane];
  float2 ww = ((const float2*)Wm2)[lane];
  float bsc = bm2[0];
  for (int p = gwave * 2; p < P; p += nw * 2){
    int p1ok = (p + 1 < P);
    int s0 = src[p], d0 = dst[p];
    int s1 = p1ok ? src[p + 1] : s0;
    int d1 = p1ok ? dst[p + 1] : d0;
    float2 a0 = __half22float2(A2[(size_t)s0 * 64 + lane]);
    float2 b0 = __half22float2(B2[(size_t)d0 * 64 + lane]);
    float2 a1 = __half22float2(A2[(size_t)s1 * 64 + lane]);
    float2 b1 = __half22float2(B2[(size_t)d1 * 64 + lane]);
    float zx0 = fmaxf(a0.x + b0.x + bb.x, 0.f);
    float zy0 = fmaxf(a0.y + b0.y + bb.y, 0.f);
    float zx1 = fmaxf(a1.x + b1.x + bb.x, 0.f);
    float zy1 = fmaxf(a1.y + b1.y + bb.y, 0.f);
    float v0 = zx0 * ww.x + zy0 * ww.y;
    float v1 = zx1 * ww.x + zy1 * ww.y;
    #pragma unroll
    for (int off = 32; off > 0; off >>= 1){
      v0 += __shfl_down(v0, off, 64);
      v1 += __shfl_down(v1, off, 64);
    }
    if (lane == 0){
      outp[p] = v0 + bsc;
      if (p1ok) outp[p + 1] = v1 + bsc;
    }
  }
}

// ---------------- launch ----------------

extern "C" void kernel_launch(void* const* d_in, const int* in_sizes, int n_in,
                              void* d_out, int out_size, void* d_ws, size_t ws_size,
                              hipStream_t stream){
  const float* x   = (const float*)d_in[0];
  const int*   ei  = (const int*)  d_in[1];
  const int*   ep  = (const int*)  d_in[2];
  const float* W1  = (const float*)d_in[3];
  const float* b1  = (const float*)d_in[4];
  const float* W2  = (const float*)d_in[5];
  const float* b2  = (const float*)d_in[6];
  const float* Wm1 = (const float*)d_in[7];
  const float* bm1 = (const float*)d_in[8];
  const float* Wm2 = (const float*)d_in[9];
  const float* bm2 = (const float*)d_in[10];
  float* outp = (float*)d_out;

  const int N = in_sizes[0] / NCH;
  const int E = in_sizes[1] / 2;
  const int P = in_sizes[2] / 2;
  const int NB = (N + G_NODES - 1) / G_NODES;   // 391 for N=100000

  // workspace layout
  char* base = (char*)d_ws;
  size_t off = 0;
  int*      counts      = (int*)     (base + off); off = align256(off + (size_t)N * 4);
  int*      offs        = (int*)     (base + off); off = align256(off + (size_t)N * 4);
  float*    dinv        = (float*)   (base + off); off = align256(off + (size_t)N * 4);
  int*      gcur        = (int*)     (base + off); off = align256(off + (size_t)NB * 4);
  int*      bbase       = (int*)     (base + off); off = align256(off + (size_t)NB * 4);
  unsigned* bucketed    = (unsigned*)(base + off); off = align256(off + (size_t)NB * RCAP * 4);
  int*      rows_sorted = (int*)     (base + off); off = align256(off + (size_t)E * 4);
  short*    wt_planes   = (short*)   (base + off); off = align256(off + (size_t)8 * 128 * 128 * 2);
  float*    hbuf        = (float*)   (base + off); off = align256(off + (size_t)N * NCH * 4);
  __half*   sA          = (__half*)  (base + off); off = align256(off + (size_t)N * NCH * 2);
  __half*   sB          = (__half*)  (base + off); off = align256(off + (size_t)N * NCH * 2);
  (void)ws_size; (void)n_in; (void)out_size;

  short* W1hi  = wt_planes + 0 * 16384;
  short* W1lo  = wt_planes + 1 * 16384;
  short* W2hi  = wt_planes + 2 * 16384;
  short* W2lo  = wt_planes + 3 * 16384;
  short* Wm1ahi= wt_planes + 4 * 16384;
  short* Wm1alo= wt_planes + 5 * 16384;
  short* Wm1bhi= wt_planes + 6 * 16384;
  short* Wm1blo= wt_planes + 7 * 16384;

  const int* row = ei;         // edge_index[0] = source
  const int* col = ei + E;     // edge_index[1] = target
  const int* psrc = ep;
  const int* pdst = ep + P;

  hipMemsetAsync(gcur, 0, (size_t)NB * 4, stream);

  binA_kernel <<<(E + EPB - 1) / EPB, 256, 0, stream>>>(row, col, gcur, bucketed, E, NB);
  bscan_kernel<<<1, 256, 0, stream>>>(gcur, bbase, NB);
  binB_kernel <<<NB, 256, 0, stream>>>(bucketed, gcur, bbase, rows_sorted, offs, counts, dinv, N);

  wsplit_kernel<<<64, 256, 0, stream>>>(W1,              W1hi,   W1lo);
  wsplit_kernel<<<64, 256, 0, stream>>>(W2,              W2hi,   W2lo);
  wsplit_kernel<<<64, 256, 0, stream>>>(Wm1,             Wm1ahi, Wm1alo);
  wsplit_kernel<<<64, 256, 0, stream>>>(Wm1 + 128 * 128, Wm1bhi, Wm1blo);

  int gemm_grid = (N + 127) / 128;
  int agg_grid  = (N + 3) / 4;

  // conv1: s1 = fp16(dinv * (x@W1));  h1 = relu(dinv*(s1[c] + sum s1[r]) + b1)
  gemm_mfma<<<gemm_grid, 256, 0, stream>>>(x, W1hi, W1lo, dinv, sA, N, 1);
  agg_kernel<<<agg_grid, 256, 0, stream>>>((const __half2*)sA, dinv, offs, counts, rows_sorted, b1, hbuf, N, 1);
  // conv2: s2 = fp16(dinv * (h1@W2)); h2 = dinv*(s2[c] + sum s2[r]) + b2
  gemm_mfma<<<gemm_grid, 256, 0, stream>>>(hbuf, W2hi, W2lo, dinv, sB, N, 1);
  agg_kernel<<<agg_grid, 256, 0, stream>>>((const __half2*)sB, dinv, offs, counts, rows_sorted, b2, hbuf, N, 0);
  // pair head precompute: A = h2 @ Wm1[:128], B = h2 @ Wm1[128:]  (fp16)
  gemm_mfma<<<gemm_grid, 256, 0, stream>>>(hbuf, Wm1ahi, Wm1alo, dinv, sA, N, 0);
  gemm_mfma<<<gemm_grid, 256, 0, stream>>>(hbuf, Wm1bhi, Wm1blo, dinv, sB, N, 0);
  // out[p] = relu(A[src]+B[dst]+bm1) @ Wm2 + bm2
  pair_kernel<<<8192, 256, 0, stream>>>((const __half2*)sA, (const __half2*)sB, psrc, pdst, bm1, Wm2, bm2, outp, P);
}

// Round 6
// 403.632 us; speedup vs baseline: 1.7906x; 1.2435x over previous
//
#include <hip/hip_runtime.h>
#include <hip/hip_fp16.h>

#define NCH 128
#define G_NODES 256      // nodes per bucket
#define EPB 4096         // edges per block, pass A
#define RCAP 4864        // per-bucket edge capacity
#define MAXNB 512        // max buckets (N <= 128k)
#define KST 40           // LDS row stride in 2B elems (80B -> 2-way conflict = free)

typedef __attribute__((ext_vector_type(8))) short short8;
typedef _Float16 half8 __attribute__((ext_vector_type(8)));
typedef __attribute__((ext_vector_type(4))) float floatx4;

static inline size_t align256(size_t x){ return (x + 255) & ~(size_t)255; }

// ---------------- Pass A: LDS-binned edge bucketing ----------------
__global__ __launch_bounds__(256) void binA_kernel(
    const int* __restrict__ row, const int* __restrict__ col,
    int* __restrict__ gcur, unsigned* __restrict__ bucketed, int E, int NB){
  __shared__ int cnt[MAXNB];
  __shared__ int lbase[MAXNB];
  __shared__ int gbase[MAXNB];
  __shared__ unsigned sorted[EPB];
  __shared__ unsigned short binOf[EPB];
  __shared__ int sh[256];
  __shared__ int carry;
  int t = threadIdx.x;
  int e0 = blockIdx.x * EPB;
  int ecnt = min(EPB, E - e0);
  for (int i = t; i < NB; i += 256) cnt[i] = 0;
  if (t == 0) carry = 0;
  __syncthreads();
  unsigned rec[16]; int bn[16]; int rk[16];
  #pragma unroll
  for (int i = 0; i < 16; i++){
    int e = e0 + i * 256 + t;
    if (e < E){
      int r = row[e], c = col[e];
      bn[i]  = c >> 8;
      rec[i] = (unsigned)r | ((unsigned)(c & 255) << 17);
      rk[i]  = atomicAdd(&cnt[bn[i]], 1);
    } else bn[i] = -1;
  }
  __syncthreads();
  for (int start = 0; start < NB; start += 256){
    int i = start + t;
    int v = (i < NB) ? cnt[i] : 0;
    sh[t] = v; __syncthreads();
    for (int off = 1; off < 256; off <<= 1){
      int val = (t >= off) ? sh[t - off] : 0;
      __syncthreads(); sh[t] += val; __syncthreads();
    }
    if (i < NB) lbase[i] = sh[t] - v + carry;
    __syncthreads();
    if (t == 255) carry += sh[255];
    __syncthreads();
  }
  for (int i = t; i < NB; i += 256){
    int c = cnt[i];
    gbase[i] = (c > 0) ? atomicAdd(&gcur[i], c) : 0;
  }
  __syncthreads();
  #pragma unroll
  for (int i = 0; i < 16; i++){
    if (bn[i] >= 0){
      int pos = lbase[bn[i]] + rk[i];
      sorted[pos] = rec[i];
      binOf[pos]  = (unsigned short)bn[i];
    }
  }
  __syncthreads();
  for (int idx = t; idx < ecnt; idx += 256){
    int b = binOf[idx];
    int gpos = gbase[b] + (idx - lbase[b]);
    if (gpos < RCAP) bucketed[(size_t)b * RCAP + gpos] = sorted[idx];
  }
}

__global__ void bscan_kernel(const int* __restrict__ gcur, int* __restrict__ bbase, int nb){
  __shared__ int sh[256];
  __shared__ int carry;
  int t = threadIdx.x;
  if (t == 0) carry = 0;
  __syncthreads();
  for (int start = 0; start < nb; start += 256){
    int i = start + t;
    int v = (i < nb) ? min(gcur[i], RCAP) : 0;
    int orig = v;
    sh[t] = v; __syncthreads();
    for (int off = 1; off < 256; off <<= 1){
      int val = (t >= off) ? sh[t - off] : 0;
      __syncthreads(); sh[t] += val; __syncthreads();
    }
    if (i < nb) bbase[i] = sh[t] - orig + carry;
    __syncthreads();
    if (t == 255) carry += sh[255];
    __syncthreads();
  }
}

// ---------------- Pass B: per-bucket LDS counting sort -> final CSR ----------------
__global__ __launch_bounds__(256) void binB_kernel(
    const unsigned* __restrict__ bucketed, const int* __restrict__ gcur,
    const int* __restrict__ bbase, int* __restrict__ rows_sorted,
    int* __restrict__ offs, int* __restrict__ counts, float* __restrict__ dinv, int N){
  __shared__ unsigned ledge[RCAP];
  __shared__ int cnt[G_NODES];
  __shared__ int cnt2[G_NODES];
  __shared__ int lex[G_NODES];
  __shared__ int sh[256];
  int b = blockIdx.x, t = threadIdx.x;
  int size = min(gcur[b], RCAP);
  int base = bbase[b];
  int n0 = b * G_NODES;
  cnt[t] = 0; cnt2[t] = 0;
  __syncthreads();
  for (int i = t; i < size; i += 256){
    unsigned v = bucketed[(size_t)b * RCAP + i];
    ledge[i] = v;
    atomicAdd(&cnt[v >> 17], 1);
  }
  __syncthreads();
  {
    int v = cnt[t];
    sh[t] = v; __syncthreads();
    for (int off = 1; off < 256; off <<= 1){
      int val = (t >= off) ? sh[t - off] : 0;
      __syncthreads(); sh[t] += val; __syncthreads();
    }
    lex[t] = sh[t] - v;
    int n = n0 + t;
    if (n < N){
      counts[n] = v;
      offs[n]   = base + sh[t] - v;
      dinv[n]   = rsqrtf((float)v + 1.0f);
    }
  }
  __syncthreads();
  for (int i = t; i < size; i += 256){
    unsigned v = ledge[i];
    int node = v >> 17;
    int pos = lex[node] + atomicAdd(&cnt2[node], 1);
    rows_sorted[base + pos] = (int)(v & 0x1FFFFu);
  }
}

// ---------------- W prep: all planes in one kernel ----------------
// planes layout: [mat][hi/lo][n][k], 16384 shorts each.
// mat 0 = W1 (bf16 split, for fp32-input GEMM); mat 1..3 = W2, Wm1a, Wm1b (f16 split).
__global__ void wprep_kernel(const float* __restrict__ W1, const float* __restrict__ W2,
                             const float* __restrict__ Wm1, short* __restrict__ planes){
  int mat = blockIdx.x >> 6;
  int idx = ((blockIdx.x & 63) << 8) + threadIdx.x;   // 0..16383
  int k = idx >> 7, n = idx & 127;
  const float* src = (mat == 0) ? W1 : (mat == 1) ? W2 : (mat == 2) ? Wm1 : (Wm1 + 16384);
  float x = src[idx];
  short hs, ls;
  if (mat == 0){
    unsigned u = __float_as_uint(x);
    hs = (short)(u >> 16);
    float hf = __uint_as_float(u & 0xFFFF0000u);
    ls = (short)(__float_as_uint(x - hf) >> 16);
  } else {
    __half h = __float2half(x);
    __half l = __float2half(x - __half2float(h));
    hs = __half_as_short(h); ls = __half_as_short(l);
  }
  planes[(size_t)(2 * mat) * 16384 + n * 128 + k]     = hs;
  planes[(size_t)(2 * mat + 1) * 16384 + n * 128 + k] = ls;
}

// ---------------- GEMM (fp32 input): [nrows,128]@[128,128], 3-MFMA bf16 split ----------------
// 512 threads, 8 waves, 16 rows/wave.
__global__ __launch_bounds__(512, 4) void gemm_f32(
    const float* __restrict__ X, const short* __restrict__ Whi_,
    const short* __restrict__ Wlo_, const float* __restrict__ scale,
    __half* __restrict__ O, int nrows, int do_scale){
  __shared__ short Xhi[128 * KST];
  __shared__ short Xlo[128 * KST];
  __shared__ short Whi[128 * KST];
  __shared__ short Wlo[128 * KST];
  int t = threadIdx.x;
  int w = t >> 6, lane = t & 63;
  int m = lane & 15, q = lane >> 4;
  int row0 = blockIdx.x * 128;
  floatx4 acc[8];
  #pragma unroll
  for (int ct = 0; ct < 8; ct++) acc[ct] = (floatx4)0.f;

  for (int kc = 0; kc < 4; kc++){
    int k0 = kc * 32;
    __syncthreads();
    #pragma unroll
    for (int qq = 0; qq < 2; qq++){
      int f = t + 512 * qq;     // float4 id 0..1023
      int r = f >> 3, kq = f & 7;
      int gr = row0 + r;
      int grc = (gr < nrows) ? gr : 0;
      float4 v = *(const float4*)(X + (size_t)grc * NCH + k0 + kq * 4);
      short h[4], l[4];
      float vv[4] = {v.x, v.y, v.z, v.w};
      #pragma unroll
      for (int j = 0; j < 4; j++){
        unsigned u = __float_as_uint(vv[j]);
        h[j] = (short)(u >> 16);
        float hf = __uint_as_float(u & 0xFFFF0000u);
        l[j] = (short)(__float_as_uint(vv[j] - hf) >> 16);
      }
      *(uint2*)(Xhi + r * KST + kq * 4) = *(uint2*)h;
      *(uint2*)(Xlo + r * KST + kq * 4) = *(uint2*)l;
    }
    {
      int n = t >> 2, kq = t & 3;   // 512 uint4 loads per plane
      *(uint4*)(Whi + n * KST + kq * 8) = *(const uint4*)(Whi_ + n * NCH + k0 + kq * 8);
      *(uint4*)(Wlo + n * KST + kq * 8) = *(const uint4*)(Wlo_ + n * NCH + k0 + kq * 8);
    }
    __syncthreads();
    short8 a_hi = *(const short8*)(Xhi + (w * 16 + m) * KST + q * 8);
    short8 a_lo = *(const short8*)(Xlo + (w * 16 + m) * KST + q * 8);
    #pragma unroll
    for (int ct = 0; ct < 8; ct++){
      short8 b_hi = *(const short8*)(Whi + (ct * 16 + m) * KST + q * 8);
      short8 b_lo = *(const short8*)(Wlo + (ct * 16 + m) * KST + q * 8);
      acc[ct] = __builtin_amdgcn_mfma_f32_16x16x32_bf16(a_hi, b_hi, acc[ct], 0, 0, 0);
      acc[ct] = __builtin_amdgcn_mfma_f32_16x16x32_bf16(a_lo, b_hi, acc[ct], 0, 0, 0);
      acc[ct] = __builtin_amdgcn_mfma_f32_16x16x32_bf16(a_hi, b_lo, acc[ct], 0, 0, 0);
    }
  }
  #pragma unroll
  for (int r = 0; r < 4; r++){
    int grow = row0 + w * 16 + q * 4 + r;
    if (grow < nrows){
      float sc = do_scale ? scale[grow] : 1.0f;
      #pragma unroll
      for (int ct = 0; ct < 8; ct++)
        O[(size_t)grow * NCH + ct * 16 + m] = __float2half(acc[ct][r] * sc);
    }
  }
}

// ---------------- GEMM (fp16 input): 2-MFMA f16, NCT col-tiles (8 or 16) ----------------
template<int NCT>
__global__ __launch_bounds__(512, 4) void gemm_f16k(
    const __half* __restrict__ X,
    const short* __restrict__ Whi0, const short* __restrict__ Wlo0,
    const short* __restrict__ Whi1, const short* __restrict__ Wlo1,
    const float* __restrict__ scale,
    __half* __restrict__ O0, __half* __restrict__ O1, int nrows, int do_scale){
  __shared__ short Xs[128 * KST];
  __shared__ short Whs[NCT * 16 * KST];
  __shared__ short Wls[NCT * 16 * KST];
  int t = threadIdx.x;
  int w = t >> 6, lane = t & 63;
  int m = lane & 15, q = lane >> 4;
  int row0 = blockIdx.x * 128;
  floatx4 acc[NCT];
  #pragma unroll
  for (int ct = 0; ct < NCT; ct++) acc[ct] = (floatx4)0.f;

  for (int kc = 0; kc < 4; kc++){
    int k0 = kc * 32;
    __syncthreads();
    {
      int r = t >> 2, kq = t & 3;   // 512 uint4 loads of X
      int gr = row0 + r;
      int grc = (gr < nrows) ? gr : 0;
      *(uint4*)(Xs + r * KST + kq * 8) = *(const uint4*)(X + (size_t)grc * NCH + k0 + kq * 8);
    }
    #pragma unroll
    for (int i = t; i < NCT * 16 * 4; i += 512){
      int n = i >> 2, kq = i & 3;
      const short* sh = (n < 128) ? (Whi0 + n * NCH) : (Whi1 + (n - 128) * NCH);
      const short* sl = (n < 128) ? (Wlo0 + n * NCH) : (Wlo1 + (n - 128) * NCH);
      *(uint4*)(Whs + n * KST + kq * 8) = *(const uint4*)(sh + k0 + kq * 8);
      *(uint4*)(Wls + n * KST + kq * 8) = *(const uint4*)(sl + k0 + kq * 8);
    }
    __syncthreads();
    half8 a = *(const half8*)(Xs + (w * 16 + m) * KST + q * 8);
    #pragma unroll
    for (int ct = 0; ct < NCT; ct++){
      half8 bh = *(const half8*)(Whs + (ct * 16 + m) * KST + q * 8);
      half8 bl = *(const half8*)(Wls + (ct * 16 + m) * KST + q * 8);
      acc[ct] = __builtin_amdgcn_mfma_f32_16x16x32_f16(a, bh, acc[ct], 0, 0, 0);
      acc[ct] = __builtin_amdgcn_mfma_f32_16x16x32_f16(a, bl, acc[ct], 0, 0, 0);
    }
  }
  #pragma unroll
  for (int r = 0; r < 4; r++){
    int grow = row0 + w * 16 + q * 4 + r;
    if (grow < nrows){
      float sc = do_scale ? scale[grow] : 1.0f;
      #pragma unroll
      for (int ct = 0; ct < NCT; ct++){
        __half val = __float2half(acc[ct][r] * sc);
        if (ct < 8) O0[(size_t)grow * NCH + ct * 16 + m] = val;
        else        O1[(size_t)grow * NCH + (ct - 8) * 16 + m] = val;
      }
    }
  }
}

// ---------------- GCN aggregation: wave per node, 16B/lane gathers ----------------
// lane = (g,h): g=lane>>4 edge subgroup (4 edges in flight), h=lane&15 channel chunk.
// out[c] = maybe_relu( dinv[c]*(s[c] + sum s[r]) + bias ), fp16 in/out.
__global__ __launch_bounds__(256) void agg_kernel(
    const __half* __restrict__ s, const float* __restrict__ dinv,
    const int* __restrict__ offs, const int* __restrict__ counts,
    const int* __restrict__ rows_sorted, const float* __restrict__ bias,
    __half* __restrict__ outp, int N, int do_relu){
  int wave = (int)((blockIdx.x * blockDim.x + threadIdx.x) >> 6);
  int lane = threadIdx.x & 63;
  if (wave >= N) return;
  int c = wave;
  int g = lane >> 4, h = lane & 15;
  float acc[8] = {0.f,0.f,0.f,0.f,0.f,0.f,0.f,0.f};
  if (g == 0){
    uint4 v = *(const uint4*)(s + (size_t)c * NCH + h * 8);
    const __half2* hp = (const __half2*)&v;
    #pragma unroll
    for (int i = 0; i < 4; i++){
      float2 f = __half22float2(hp[i]);
      acc[2*i] += f.x; acc[2*i+1] += f.y;
    }
  }
  int off = offs[c], cnt = counts[c];
  for (int chunk = 0; chunk < cnt; chunk += 64){
    int nn = min(64, cnt - chunk);
    int myidx = (lane < nn) ? rows_sorted[off + chunk + lane] : 0;
    int jmax = (nn + 3) >> 2;
    #pragma unroll 4
    for (int j = 0; j < jmax; j++){
      int e = 4 * j + g;
      int r = __shfl(myidx, e & 63, 64);
      if (e < nn){
        uint4 v = *(const uint4*)(s + (size_t)r * NCH + h * 8);
        const __half2* hp = (const __half2*)&v;
        #pragma unroll
        for (int i = 0; i < 4; i++){
          float2 f = __half22float2(hp[i]);
          acc[2*i] += f.x; acc[2*i+1] += f.y;
        }
      }
    }
  }
  #pragma unroll
  for (int i = 0; i < 8; i++){
    acc[i] += __shfl_xor(acc[i], 16, 64);
    acc[i] += __shfl_xor(acc[i], 32, 64);
  }
  if (g == 0){
    float di = dinv[c];
    float4 b0 = *(const float4*)(bias + h * 8);
    float4 b1 = *(const float4*)(bias + h * 8 + 4);
    float o[8];
    o[0] = di*acc[0]+b0.x; o[1] = di*acc[1]+b0.y; o[2] = di*acc[2]+b0.z; o[3] = di*acc[3]+b0.w;
    o[4] = di*acc[4]+b1.x; o[5] = di*acc[5]+b1.y; o[6] = di*acc[6]+b1.z; o[7] = di*acc[7]+b1.w;
    if (do_relu){
      #pragma unroll
      for (int i = 0; i < 8; i++) o[i] = fmaxf(o[i], 0.f);
    }
    __half2 packed[4];
    #pragma unroll
    for (int i = 0; i < 4; i++) packed[i] = __floats2half2_rn(o[2*i], o[2*i+1]);
    *(uint4*)(outp + (size_t)c * NCH + h * 8) = *(uint4*)packed;
  }
}

// ---------------- Pair head: wave per 2 pairs, 16B/lane ----------------
// lane = (g,h): g 0:A[p0] 1:B[p0] 2:A[p1] 3:B[p1]; h = channel chunk.
__global__ __launch_bounds__(256) void pair_kernel(
    const __half* __restrict__ A, const __half* __restrict__ B,
    const int* __restrict__ src, const int* __restrict__ dst,
    const float* __restrict__ bm1, const float* __restrict__ Wm2,
    const float* __restrict__ bm2, float* __restrict__ outp, int P){
  int gwave = (int)((blockIdx.x * blockDim.x + threadIdx.x) >> 6);
  int lane  = threadIdx.x & 63;
  int nw    = (int)((gridDim.x * blockDim.x) >> 6);
  int g = lane >> 4, h = lane & 15;
  float bb[8], ww[8];
  {
    float4 t0 = *(const float4*)(bm1 + h * 8);
    float4 t1 = *(const float4*)(bm1 + h * 8 + 4);
    bb[0]=t0.x; bb[1]=t0.y; bb[2]=t0.z; bb[3]=t0.w;
    bb[4]=t1.x; bb[5]=t1.y; bb[6]=t1.z; bb[7]=t1.w;
    float4 w0 = *(const float4*)(Wm2 + h * 8);
    float4 w1 = *(const float4*)(Wm2 + h * 8 + 4);
    ww[0]=w0.x; ww[1]=w0.y; ww[2]=w0.z; ww[3]=w0.w;
    ww[4]=w1.x; ww[5]=w1.y; ww[6]=w1.z; ww[7]=w1.w;
  }
  float bsc = bm2[0];
  const __half* basep = (g & 1) ? B : A;
  for (int p0 = gwave * 2; p0 < P; p0 += nw * 2){
    int pi = p0 + (g >> 1);
    int piX = (pi < P) ? pi : p0;
    int node = (g & 1) ? dst[piX] : src[piX];
    uint4 v = *(const uint4*)(basep + (size_t)node * NCH + h * 8);
    const __half2* hp = (const __half2*)&v;
    float f[8];
    #pragma unroll
    for (int i = 0; i < 4; i++){
      float2 t = __half22float2(hp[i]);
      f[2*i] = t.x; f[2*i+1] = t.y;
    }
    float partial = 0.f;
    #pragma unroll
    for (int i = 0; i < 8; i++){
      float other = __shfl_xor(f[i], 16, 64);
      float zi = fmaxf(f[i] + other + bb[i], 0.f);
      partial += zi * ww[i];
    }
    partial += __shfl_xor(partial, 1, 64);
    partial += __shfl_xor(partial, 2, 64);
    partial += __shfl_xor(partial, 4, 64);
    partial += __shfl_xor(partial, 8, 64);
    if ((lane & 31) == 0 && pi < P) outp[pi] = partial + bsc;
  }
}

// ---------------- launch ----------------

extern "C" void kernel_launch(void* const* d_in, const int* in_sizes, int n_in,
                              void* d_out, int out_size, void* d_ws, size_t ws_size,
                              hipStream_t stream){
  const float* x   = (const float*)d_in[0];
  const int*   ei  = (const int*)  d_in[1];
  const int*   ep  = (const int*)  d_in[2];
  const float* W1  = (const float*)d_in[3];
  const float* b1  = (const float*)d_in[4];
  const float* W2  = (const float*)d_in[5];
  const float* b2  = (const float*)d_in[6];
  const float* Wm1 = (const float*)d_in[7];
  const float* bm1 = (const float*)d_in[8];
  const float* Wm2 = (const float*)d_in[9];
  const float* bm2 = (const float*)d_in[10];
  float* outp = (float*)d_out;

  const int N = in_sizes[0] / NCH;
  const int E = in_sizes[1] / 2;
  const int P = in_sizes[2] / 2;
  const int NB = (N + G_NODES - 1) / G_NODES;

  char* base = (char*)d_ws;
  size_t off = 0;
  int*      counts      = (int*)     (base + off); off = align256(off + (size_t)N * 4);
  int*      offs        = (int*)     (base + off); off = align256(off + (size_t)N * 4);
  float*    dinv        = (float*)   (base + off); off = align256(off + (size_t)N * 4);
  int*      gcur        = (int*)     (base + off); off = align256(off + (size_t)NB * 4);
  int*      bbase       = (int*)     (base + off); off = align256(off + (size_t)NB * 4);
  unsigned* bucketed    = (unsigned*)(base + off); off = align256(off + (size_t)NB * RCAP * 4);
  int*      rows_sorted = (int*)     (base + off); off = align256(off + (size_t)E * 4);
  short*    planes      = (short*)   (base + off); off = align256(off + (size_t)8 * 16384 * 2);
  __half*   sbuf        = (__half*)  (base + off); off = align256(off + (size_t)N * NCH * 2);
  __half*   hbuf        = (__half*)  (base + off); off = align256(off + (size_t)N * NCH * 2);
  __half*   sA          = (__half*)  (base + off); off = align256(off + (size_t)N * NCH * 2);
  __half*   sB          = (__half*)  (base + off); off = align256(off + (size_t)N * NCH * 2);
  (void)ws_size; (void)n_in; (void)out_size;

  short* W1hi = planes + 0 * 16384;
  short* W1lo = planes + 1 * 16384;
  short* W2hi = planes + 2 * 16384;
  short* W2lo = planes + 3 * 16384;
  short* Wahi = planes + 4 * 16384;
  short* Walo = planes + 5 * 16384;
  short* Wbhi = planes + 6 * 16384;
  short* Wblo = planes + 7 * 16384;

  const int* row = ei;       // edge_index[0] = source
  const int* col = ei + E;   // edge_index[1] = target
  const int* psrc = ep;
  const int* pdst = ep + P;

  hipMemsetAsync(gcur, 0, (size_t)NB * 4, stream);

  binA_kernel <<<(E + EPB - 1) / EPB, 256, 0, stream>>>(row, col, gcur, bucketed, E, NB);
  bscan_kernel<<<1, 256, 0, stream>>>(gcur, bbase, NB);
  binB_kernel <<<NB, 256, 0, stream>>>(bucketed, gcur, bbase, rows_sorted, offs, counts, dinv, N);
  wprep_kernel<<<256, 256, 0, stream>>>(W1, W2, Wm1, planes);

  int gemm_grid = (N + 127) / 128;
  int agg_grid  = (N + 3) / 4;

  // conv1: s1 = fp16(dinv*(x@W1)); h1 = fp16(relu(dinv*(s1[c]+sum s1[r]) + b1))
  gemm_f32<<<gemm_grid, 512, 0, stream>>>(x, W1hi, W1lo, dinv, sbuf, N, 1);
  agg_kernel<<<agg_grid, 256, 0, stream>>>(sbuf, dinv, offs, counts, rows_sorted, b1, hbuf, N, 1);
  // conv2: s2 = fp16(dinv*(h1@W2)); h2 = fp16(dinv*(s2[c]+sum s2[r]) + b2)
  gemm_f16k<8><<<gemm_grid, 512, 0, stream>>>(hbuf, W2hi, W2lo, W2hi, W2lo, dinv, sbuf, sbuf, N, 1);
  agg_kernel<<<agg_grid, 256, 0, stream>>>(sbuf, dinv, offs, counts, rows_sorted, b2, hbuf, N, 0);
  // pair precompute (dual): sA = h2@Wm1a, sB = h2@Wm1b  (fp16)
  gemm_f16k<16><<<gemm_grid, 512, 0, stream>>>(hbuf, Wahi, Walo, Wbhi, Wblo, dinv, sA, sB, N, 0);
  // out[p] = relu(A[src]+B[dst]+bm1)@Wm2 + bm2
  pair_kernel<<<8192, 256, 0, stream>>>(sA, sB, psrc, pdst, bm1, Wm2, bm2, outp, P);
}